// Round 1
// baseline (1110.217 us; speedup 1.0000x reference)
//
#include <hip/hip_runtime.h>

#define NUM_PAIRS 10

__global__ void zero_kernel(float* __restrict__ out, int n) {
    int i = blockIdx.x * blockDim.x + threadIdx.x;
    if (i < n) out[i] = 0.0f;
}

__global__ __launch_bounds__(256) void force_kernel(
    const float* __restrict__ raw_charges,
    const float* __restrict__ A,
    const float* __restrict__ rho,
    const float* __restrict__ C,
    const float* __restrict__ distances,
    const float* __restrict__ inv_d2_arr,
    const float* __restrict__ uv,            // [E,3]
    const int*   __restrict__ edge_src,      // edge_index row 0
    const int*   __restrict__ pair_indices,
    const int*   __restrict__ src_elem,
    const int*   __restrict__ tgt_elem,
    float* __restrict__ forces,              // [n_nodes,3]
    int n_edges)
{
    __shared__ float s_AoR[NUM_PAIRS];    // A/rho
    __shared__ float s_invRho[NUM_PAIRS]; // 1/rho
    __shared__ float s_C6[NUM_PAIRS];     // 6*C
    __shared__ float s_qq[16];            // q[s]*q[t]

    const int t = threadIdx.x;
    if (t < NUM_PAIRS) {
        float r = rho[t];
        float ir = 1.0f / r;
        s_invRho[t] = ir;
        s_AoR[t]    = A[t] * ir;
        s_C6[t]     = 6.0f * C[t];
    }
    if (t < 16) {
        float q0 = raw_charges[0];
        // charges: [Cd, Se, S, Zn] = [q0, -q0, raw[1], raw[2]]
        float qs0 = q0;
        float qs1 = -q0;
        float qs2 = raw_charges[1];
        float qs3 = raw_charges[2];
        float qa = (t & 3) == 0 ? qs0 : (t & 3) == 1 ? qs1 : (t & 3) == 2 ? qs2 : qs3;
        int hb = t >> 2;
        float qb = hb == 0 ? qs0 : hb == 1 ? qs1 : hb == 2 ? qs2 : qs3;
        s_qq[t] = qa * qb;
    }
    __syncthreads();

    int e = blockIdx.x * blockDim.x + t;
    if (e >= n_edges) return;

    float d      = distances[e];
    float inv_d2 = inv_d2_arr[e];
    int   p      = pair_indices[e];
    int   se     = src_elem[e];
    int   te     = tgt_elem[e];

    float inv_d  = inv_d2 * d;   // 1/d without a division
    float inv_d6 = inv_d2 * inv_d2 * inv_d2;

    float pot  = s_AoR[p] * __expf(-d * s_invRho[p]) - s_C6[p] * inv_d6 * inv_d;
    float coul = s_qq[(te << 2) | se] * inv_d2;   // product is symmetric in (s,t)
    float total = pot + coul;

    float ux = uv[3 * e + 0];
    float uy = uv[3 * e + 1];
    float uz = uv[3 * e + 2];

    int node = edge_src[e];
    float* dst = forces + 3 * node;
    atomicAdd(dst + 0, -total * ux);
    atomicAdd(dst + 1, -total * uy);
    atomicAdd(dst + 2, -total * uz);
}

extern "C" void kernel_launch(void* const* d_in, const int* in_sizes, int n_in,
                              void* d_out, int out_size, void* d_ws, size_t ws_size,
                              hipStream_t stream) {
    const float* raw_charges = (const float*)d_in[0];
    const float* A           = (const float*)d_in[1];
    const float* rho         = (const float*)d_in[2];
    const float* C           = (const float*)d_in[3];
    const float* distances   = (const float*)d_in[4];
    const float* inv_d2      = (const float*)d_in[5];
    const float* uv          = (const float*)d_in[6];
    const int*   edge_index  = (const int*)d_in[7];   // [2, E]
    const int*   pair_idx    = (const int*)d_in[8];
    const int*   src_elem    = (const int*)d_in[9];
    const int*   tgt_elem    = (const int*)d_in[10];

    float* forces = (float*)d_out;
    const int n_edges = in_sizes[4];
    const int n_out   = out_size;          // n_nodes * 3

    const int ZB = 256;
    zero_kernel<<<(n_out + ZB - 1) / ZB, ZB, 0, stream>>>(forces, n_out);

    const int B = 256;
    const int grid = (n_edges + B - 1) / B;
    force_kernel<<<grid, B, 0, stream>>>(raw_charges, A, rho, C,
                                         distances, inv_d2, uv,
                                         edge_index /* row 0 */, pair_idx,
                                         src_elem, tgt_elem,
                                         forces, n_edges);
}